// Round 2
// baseline (169831.116 us; speedup 1.0000x reference)
//
#include <hip/hip_runtime.h>
#include <hip/hip_bf16.h>

#define NMEL 80

__device__ __forceinline__ float bf2f(unsigned short u) {
  unsigned v = ((unsigned)u) << 16; float f; __builtin_memcpy(&f, &v, 4); return f;
}
__device__ __forceinline__ unsigned short f2bf_u(float f) {
  __hip_bfloat16 h = __float2bfloat16(f); unsigned short u; __builtin_memcpy(&u, &h, 2); return u;
}
__device__ __forceinline__ float agload(const float* p) {
  return __hip_atomic_load(p, __ATOMIC_RELAXED, __HIP_MEMORY_SCOPE_AGENT);
}
__device__ __forceinline__ void agstore(float* p, float v) {
  __hip_atomic_store(p, v, __ATOMIC_RELAXED, __HIP_MEMORY_SCOPE_AGENT);
}

// ---------------- workspace layout (bytes) ----------------
// attnT f32 [b][a>>2][te][a&3], pre-scaled by 2*log2(e)
constexpr size_t OFF_ATTNT = 0;
constexpr size_t SZ_ATTNT = (size_t)64 * 256 * 1024 * 4;          // 67,108,864
constexpr size_t OFF_PRE2 = OFF_ATTNT + SZ_ATTNT;                  // bf16 [64000][256]
constexpr size_t SZ_PRE2 = (size_t)64000 * 256 * 2;                // 32,768,000
constexpr size_t OFF_WIC4 = OFF_PRE2 + SZ_PRE2;                    // f32 [4][64][256][4]
constexpr size_t SZ_W4 = (size_t)4 * 64 * 256 * 4 * 4;             // 1,048,576
constexpr size_t OFF_WPRE4 = OFF_WIC4 + SZ_W4;
constexpr size_t OFF_WHH4 = OFF_WPRE4 + SZ_W4;
constexpr size_t OFF_WDECT = OFF_WHH4 + SZ_W4;                     // f32 [4][64][256]
constexpr size_t SZ_WDECT = (size_t)4 * 64 * 256 * 4;
constexpr size_t OFF_MELT = OFF_WDECT + SZ_WDECT;                  // f32 [4][128][80]
constexpr size_t SZ_MELT = (size_t)4 * 128 * 80 * 4;
constexpr size_t OFF_STOPT = OFF_MELT + SZ_MELT;                   // f32 [4][128]
constexpr size_t SZ_STOPT = (size_t)4 * 128 * 4;
constexpr size_t OFF_BIASG = OFF_STOPT + SZ_STOPT;                 // f32 [4][256]
constexpr size_t SZ_BIASG = (size_t)4 * 256 * 4;
constexpr size_t OFF_EXCH = (OFF_BIASG + SZ_BIASG + 255) & ~(size_t)255;
// exchange region (float indices)
constexpr size_t EXF_DEC = 0;                         // [2][64][4][256]
constexpr size_t EXN_DEC = (size_t)2 * 64 * 4 * 256;
constexpr size_t EXF_GH = EXF_DEC + EXN_DEC;          // [2][64][4][1024]
constexpr size_t EXN_GH = (size_t)2 * 64 * 4 * 1024;
constexpr size_t EXF_CTX = EXF_GH + EXN_GH;           // [64][4][256]
constexpr size_t EXN_CTX = (size_t)64 * 4 * 256;
constexpr size_t EXF_S = EXF_CTX + EXN_CTX;           // [64][16]
constexpr size_t EXN_S = 64 * 16;
constexpr size_t EXF_CTR = EXF_S + EXN_S;             // u32 [64][16]
constexpr size_t EXN_CTR = 64 * 16;
constexpr size_t EXCH_FLOATS = EXF_CTR + EXN_CTR;
constexpr size_t SZ_EXCH = EXCH_FLOATS * 4;
constexpr size_t WS_NEED = OFF_EXCH + SZ_EXCH;        // ~101.4 MiB

// ---------------- weight re-layout ----------------
__global__ __launch_bounds__(256) void prep_weights(
    const float* __restrict__ W_ih, const float* __restrict__ W_hh,
    const float* __restrict__ W_dec, const float* __restrict__ mel_W,
    const float* __restrict__ stop_W, const float* __restrict__ b_ih,
    const float* __restrict__ b_hh,
    float* __restrict__ Wic4, float* __restrict__ Wpre4, float* __restrict__ Whh4,
    float* __restrict__ WdecT, float* __restrict__ MelT, float* __restrict__ StopT,
    float* __restrict__ biasG) {
  int idx = blockIdx.x * 256 + threadIdx.x;
  if (idx < 262144) {
    int q = idx & 3, j = (idx >> 2) & 255, c4 = (idx >> 10) & 63, s = idx >> 16;
    int row = (j >> 6) * 256 + s * 64 + (j & 63);
    Wic4[idx] = W_ih[(size_t)row * 512 + 256 + c4 * 4 + q];
    Wpre4[idx] = W_ih[(size_t)row * 512 + c4 * 4 + q];
    Whh4[idx] = W_hh[(size_t)(j * 4 + q) * 256 + s * 64 + c4];
  } else if (idx < 262144 + 65536) {
    int k = idx - 262144;
    int a = k & 255, hh = (k >> 8) & 63, s = k >> 14;
    WdecT[k] = W_dec[(size_t)a * 256 + s * 64 + hh];
  } else if (idx < 262144 + 65536 + 40960) {
    int k = idx - (262144 + 65536);
    int m = k % 80, r = k / 80;
    int cc = r & 127, s = r >> 7;
    int col = (cc < 64) ? (s * 64 + cc) : (256 + s * 64 + (cc - 64));
    MelT[k] = mel_W[(size_t)m * 512 + col];
  } else if (idx < 262144 + 65536 + 40960 + 512) {
    int k = idx - (262144 + 65536 + 40960);
    int cc = k & 127, s = k >> 7;
    int col = (cc < 64) ? (s * 64 + cc) : (256 + s * 64 + (cc - 64));
    StopT[k] = stop_W[col];
  } else if (idx < 262144 + 65536 + 40960 + 512 + 1024) {
    int k = idx - (262144 + 65536 + 40960 + 512);
    int j = k & 255, s = k >> 8;
    int row = (j >> 6) * 256 + s * 64 + (j & 63);
    biasG[k] = b_ih[row] + b_hh[row];
  }
}

// ---------------- attn_enc GEMM: attnT[b][a>>2][te][a&3] = CE*(enc[b][te] . W_enc[a] + b_enc[a]) ----------------
__global__ __launch_bounds__(256) void attn_gemm(const float* __restrict__ enc,
                                                 const float* __restrict__ W_enc,
                                                 const float* __restrict__ b_enc,
                                                 float* __restrict__ attnT) {
  __shared__ unsigned short Alds[64 * 260];
  const int tid = threadIdx.x;
  const int row0 = blockIdx.x * 64;
  const int wv = tid >> 6, lane = tid & 63, nb = wv * 64;
  for (int idx = tid; idx < 64 * 256; idx += 256) {
    int r = idx >> 8, k = idx & 255;
    Alds[r * 260 + k] = f2bf_u(enc[(size_t)(row0 + r) * 256 + k]);
  }
  __syncthreads();
  float acc[64];
#pragma unroll
  for (int n = 0; n < 64; ++n) acc[n] = b_enc[nb + n];
  for (int k8 = 0; k8 < 256; k8 += 8) {
    ushort4 ua = *(const ushort4*)&Alds[lane * 260 + k8];
    ushort4 ub = *(const ushort4*)&Alds[lane * 260 + k8 + 4];
    float a0 = bf2f(ua.x), a1 = bf2f(ua.y), a2 = bf2f(ua.z), a3 = bf2f(ua.w);
    float a4 = bf2f(ub.x), a5 = bf2f(ub.y), a6 = bf2f(ub.z), a7 = bf2f(ub.w);
#pragma unroll
    for (int n = 0; n < 64; ++n) {
      const float4* wp = (const float4*)(W_enc + (size_t)(nb + n) * 256 + k8);
      float4 w0 = wp[0], w1 = wp[1];
      acc[n] = fmaf(a0, w0.x, acc[n]); acc[n] = fmaf(a1, w0.y, acc[n]);
      acc[n] = fmaf(a2, w0.z, acc[n]); acc[n] = fmaf(a3, w0.w, acc[n]);
      acc[n] = fmaf(a4, w1.x, acc[n]); acc[n] = fmaf(a5, w1.y, acc[n]);
      acc[n] = fmaf(a6, w1.z, acc[n]); acc[n] = fmaf(a7, w1.w, acc[n]);
    }
  }
  const float CE = 2.8853900817779268f;  // 2*log2(e)
  const int b = row0 >> 10;
  const int te = (row0 & 1023) + lane;
#pragma unroll
  for (int n = 0; n < 64; ++n) {
    int a = nb + n;
    attnT[(((size_t)b) << 18) + (((size_t)(a >> 2)) << 12) + (((size_t)te) << 2) + (a & 3)] =
        acc[n] * CE;
  }
}

// ---------------- fused prenet: pre2 = relu(relu(prev@W1^T+b1)@W2^T+b2), bf16 out ----------------
__global__ __launch_bounds__(256) void prenet_fused(const float* __restrict__ tmel,
                                                    const float* __restrict__ W1,
                                                    const float* __restrict__ b1,
                                                    const float* __restrict__ W2,
                                                    const float* __restrict__ b2,
                                                    unsigned short* __restrict__ pre2) {
  __shared__ unsigned short Alds[64 * 260];
  const int tid = threadIdx.x;
  const int row0 = blockIdx.x * 64;
  const int wv = tid >> 6, lane = tid & 63, nb = wv * 64;
  for (int idx = tid; idx < 64 * 80; idx += 256) {
    int r = idx / 80, k = idx - r * 80;
    int R = row0 + r;
    float v = (R % 1000 != 0) ? tmel[(size_t)(R - 1) * NMEL + k] : 0.f;
    Alds[r * 260 + k] = f2bf_u(v);
  }
  __syncthreads();
  float acc[64];
#pragma unroll
  for (int n = 0; n < 64; ++n) acc[n] = b1[nb + n];
  for (int k8 = 0; k8 < 80; k8 += 8) {
    ushort4 ua = *(const ushort4*)&Alds[lane * 260 + k8];
    ushort4 ub = *(const ushort4*)&Alds[lane * 260 + k8 + 4];
    float a0 = bf2f(ua.x), a1 = bf2f(ua.y), a2 = bf2f(ua.z), a3 = bf2f(ua.w);
    float a4 = bf2f(ub.x), a5 = bf2f(ub.y), a6 = bf2f(ub.z), a7 = bf2f(ub.w);
#pragma unroll
    for (int n = 0; n < 64; ++n) {
      const float4* wp = (const float4*)(W1 + (size_t)(nb + n) * 80 + k8);
      float4 w0 = wp[0], w1 = wp[1];
      acc[n] = fmaf(a0, w0.x, acc[n]); acc[n] = fmaf(a1, w0.y, acc[n]);
      acc[n] = fmaf(a2, w0.z, acc[n]); acc[n] = fmaf(a3, w0.w, acc[n]);
      acc[n] = fmaf(a4, w1.x, acc[n]); acc[n] = fmaf(a5, w1.y, acc[n]);
      acc[n] = fmaf(a6, w1.z, acc[n]); acc[n] = fmaf(a7, w1.w, acc[n]);
    }
  }
  __syncthreads();
#pragma unroll
  for (int n = 0; n < 64; ++n) Alds[lane * 260 + nb + n] = f2bf_u(fmaxf(acc[n], 0.f));
  __syncthreads();
#pragma unroll
  for (int n = 0; n < 64; ++n) acc[n] = b2[nb + n];
  for (int k8 = 0; k8 < 256; k8 += 8) {
    ushort4 ua = *(const ushort4*)&Alds[lane * 260 + k8];
    ushort4 ub = *(const ushort4*)&Alds[lane * 260 + k8 + 4];
    float a0 = bf2f(ua.x), a1 = bf2f(ua.y), a2 = bf2f(ua.z), a3 = bf2f(ua.w);
    float a4 = bf2f(ub.x), a5 = bf2f(ub.y), a6 = bf2f(ub.z), a7 = bf2f(ub.w);
#pragma unroll
    for (int n = 0; n < 64; ++n) {
      const float4* wp = (const float4*)(W2 + (size_t)(nb + n) * 256 + k8);
      float4 w0 = wp[0], w1 = wp[1];
      acc[n] = fmaf(a0, w0.x, acc[n]); acc[n] = fmaf(a1, w0.y, acc[n]);
      acc[n] = fmaf(a2, w0.z, acc[n]); acc[n] = fmaf(a3, w0.w, acc[n]);
      acc[n] = fmaf(a4, w1.x, acc[n]); acc[n] = fmaf(a5, w1.y, acc[n]);
      acc[n] = fmaf(a6, w1.z, acc[n]); acc[n] = fmaf(a7, w1.w, acc[n]);
    }
  }
  __syncthreads();
#pragma unroll
  for (int n = 0; n < 64; ++n) Alds[lane * 260 + nb + n] = f2bf_u(fmaxf(acc[n], 0.f));
  __syncthreads();
  for (int idx = tid; idx < 64 * 128; idx += 256) {
    int r = idx >> 7, k2 = (idx & 127) * 2;
    unsigned pair = (unsigned)Alds[r * 260 + k2] | ((unsigned)Alds[r * 260 + k2 + 1] << 16);
    *(unsigned*)(pre2 + (size_t)(row0 + r) * 256 + k2) = pair;
  }
}

// ---------------- persistent decoder loop ----------------
// grid = 256 WGs; b = wg&63, s = wg>>6 (slices of one b share wg%8 -> same XCD).
__global__ __launch_bounds__(256) void decoder_loop(
    const float* __restrict__ attnT, const float* __restrict__ enc,
    const unsigned short* __restrict__ pre2,
    const float* __restrict__ Wic4, const float* __restrict__ Wpre4,
    const float* __restrict__ Whh4, const float* __restrict__ WdecT,
    const float* __restrict__ MelT, const float* __restrict__ StopT,
    const float* __restrict__ biasG,
    float* exch, unsigned* ctr,
    const float* __restrict__ b_dec, const float* __restrict__ v_w,
    const float* __restrict__ v_b, const float* __restrict__ enc_mask,
    const float* __restrict__ mel_b, const float* __restrict__ stop_b,
    float* out) {
  __shared__ float dec_lds[256], v2_lds[256], p_lds[256], ctx_lds[256], gates_lds[256];
  __shared__ float pre_lds[256];
  __shared__ float ctxp_lds[1024];
  __shared__ float c_lds[64], h_lds[64];
  __shared__ float red_lds[8];
  __shared__ float stop_lds[128];
  __shared__ float sv_lds;

  const int tid = threadIdx.x;
  const int wg = blockIdx.x;
  const int b = wg & 63, s = wg >> 6;
  const int lane = tid & 63, wid = tid >> 6;
  const float CE = 2.8853900817779268f;   // 2*log2(e)
  const float L2E = 1.4426950408889634f;  // log2(e)

  if (tid < 64) c_lds[tid] = 0.f;
  v2_lds[tid] = -2.f * v_w[tid];
  {
    float sp = v_w[tid];
    for (int m = 32; m; m >>= 1) sp += __shfl_xor(sp, m);
    if (lane == 0) red_lds[wid] = sp;
  }
  __syncthreads();
  if (tid == 0) sv_lds = red_lds[0] + red_lds[1] + red_lds[2] + red_lds[3];
  __syncthreads();
  const float Sv = sv_lds;
  const float vb = v_b[0];
  const int te = s * 256 + tid;
  const float maskv = enc_mask[b * 1024 + te];
  const float bdec_r = b_dec[tid];
  const float biasg_r = biasG[s * 256 + tid];
  const float* attn_me4 = attnT + (((size_t)b) << 18) + (((size_t)te) << 2);
  const unsigned short* pre2_b = pre2 + (size_t)b * 1000 * 256;

  float* decP = exch + EXF_DEC;
  float* ghP = exch + EXF_GH;
  float* ctxP = exch + EXF_CTX;
  float* sP = exch + EXF_S;
  unsigned* ctrb = ctr + b * 16;
  unsigned epoch = 0;

  for (int it = 0; it < 1000; ++it) {
    const int par = it & 1;
    // prefetch this step's prenet activation (used after barrier 1)
    float prefv = bf2f(pre2_b[(size_t)it * 256 + tid]);
    // ---- attn_dec (pre-scaled by 2*log2e) ----
    {
      const float* dp = decP + ((size_t)(par * 64 + b) * 4) * 256 + tid;
      float d = bdec_r + agload(dp) + agload(dp + 256) + agload(dp + 512) + agload(dp + 768);
      dec_lds[tid] = d * CE;
    }
    __syncthreads();
    // ---- energy over own te: e = Sv + sum_a (-2 v[a]) * sigm-like + vb ----
    float acc = Sv;
#pragma unroll 8
    for (int a4 = 0; a4 < 64; ++a4) {
      float4 t4 = *(const float4*)(attn_me4 + (((size_t)a4) << 12));
      float4 d4 = *(const float4*)&dec_lds[a4 * 4];
      float4 v4 = *(const float4*)&v2_lds[a4 * 4];
      acc = fmaf(v4.x, __builtin_amdgcn_rcpf(1.f + __builtin_amdgcn_exp2f(t4.x + d4.x)), acc);
      acc = fmaf(v4.y, __builtin_amdgcn_rcpf(1.f + __builtin_amdgcn_exp2f(t4.y + d4.y)), acc);
      acc = fmaf(v4.z, __builtin_amdgcn_rcpf(1.f + __builtin_amdgcn_exp2f(t4.z + d4.z)), acc);
      acc = fmaf(v4.w, __builtin_amdgcn_rcpf(1.f + __builtin_amdgcn_exp2f(t4.w + d4.w)), acc);
    }
    float e = acc + vb;
    // |e| <= ||v||_1 + |v_b| ~ 10 -> exp safe without max-subtraction
    float p = (maskv != 0.f) ? __builtin_amdgcn_exp2f(e * L2E) : 0.f;
    p_lds[tid] = p;
    {
      float sp = p;
      for (int m = 32; m; m >>= 1) sp += __shfl_xor(sp, m);
      if (lane == 0) red_lds[wid] = sp;
    }
    __syncthreads();
    // ---- context partial over own te slice (enc fp32, float4) ----
    {
      int d0 = lane * 4;
      const float* ep = enc + ((size_t)(b * 1024 + s * 256 + wid * 64)) * 256 + d0;
      float c0 = 0, c1 = 0, c2 = 0, c3 = 0;
#pragma unroll 4
      for (int tt = 0; tt < 64; ++tt) {
        float pv = p_lds[wid * 64 + tt];
        float4 ev = *(const float4*)(ep + ((size_t)tt) * 256);
        c0 = fmaf(pv, ev.x, c0);
        c1 = fmaf(pv, ev.y, c1);
        c2 = fmaf(pv, ev.z, c2);
        c3 = fmaf(pv, ev.w, c3);
      }
      ctxp_lds[wid * 256 + d0 + 0] = c0;
      ctxp_lds[wid * 256 + d0 + 1] = c1;
      ctxp_lds[wid * 256 + d0 + 2] = c2;
      ctxp_lds[wid * 256 + d0 + 3] = c3;
    }
    __syncthreads();
    {
      float cp = ctxp_lds[tid] + ctxp_lds[256 + tid] + ctxp_lds[512 + tid] + ctxp_lds[768 + tid];
      agstore(ctxP + ((size_t)b * 4 + s) * 256 + tid, cp);
      if (tid == 0) agstore(sP + b * 16 + s, red_lds[0] + red_lds[1] + red_lds[2] + red_lds[3]);
    }
    pre_lds[tid] = prefv;
    // ================= barrier 1 =================
    __threadfence();
    __syncthreads();
    if (tid == 0) {
      ++epoch;
      __hip_atomic_fetch_add(ctrb, 1u, __ATOMIC_RELEASE, __HIP_MEMORY_SCOPE_AGENT);
      while (__hip_atomic_load(ctrb, __ATOMIC_ACQUIRE, __HIP_MEMORY_SCOPE_AGENT) < 4u * epoch)
        __builtin_amdgcn_s_sleep(1);
    }
    __syncthreads();
    __threadfence();
    // ---- full normalized context ----
    {
      float Ssum = agload(sP + b * 16 + 0) + agload(sP + b * 16 + 1) +
                   agload(sP + b * 16 + 2) + agload(sP + b * 16 + 3);
      float rS = 1.f / Ssum;
      const float* cp = ctxP + (size_t)b * 4 * 256 + tid;
      ctx_lds[tid] = (agload(cp) + agload(cp + 256) + agload(cp + 512) + agload(cp + 768)) * rS;
    }
    __syncthreads();
    // ---- gates for rows {wid*256 + s*64 + lane} ----
    {
      float g = biasg_r;
      const float* gp = ghP + ((size_t)(par * 64 + b) * 4) * 1024 + (wid * 256 + s * 64 + lane);
      g += agload(gp) + agload(gp + 1024) + agload(gp + 2048) + agload(gp + 3072);
      const float* wp = Wic4 + (size_t)s * 65536 + tid * 4;
      const float* wq = Wpre4 + (size_t)s * 65536 + tid * 4;
#pragma unroll 8
      for (int c4 = 0; c4 < 64; ++c4) {
        float4 wv1 = *(const float4*)(wp + (size_t)c4 * 1024);
        float4 cx = *(const float4*)&ctx_lds[c4 * 4];
        g = fmaf(wv1.x, cx.x, g); g = fmaf(wv1.y, cx.y, g);
        g = fmaf(wv1.z, cx.z, g); g = fmaf(wv1.w, cx.w, g);
        float4 wv2 = *(const float4*)(wq + (size_t)c4 * 1024);
        float4 px = *(const float4*)&pre_lds[c4 * 4];
        g = fmaf(wv2.x, px.x, g); g = fmaf(wv2.y, px.y, g);
        g = fmaf(wv2.z, px.z, g); g = fmaf(wv2.w, px.w, g);
      }
      gates_lds[tid] = g;
    }
    __syncthreads();
    // ---- LSTM pointwise for own 64 units ----
    if (tid < 64) {
      float ii = gates_lds[tid], ff = gates_lds[64 + tid];
      float gg = gates_lds[128 + tid], oo = gates_lds[192 + tid];
      float c = c_lds[tid];
      float si = __builtin_amdgcn_rcpf(1.f + __builtin_amdgcn_exp2f(-ii * L2E));
      float sf = __builtin_amdgcn_rcpf(1.f + __builtin_amdgcn_exp2f(-ff * L2E));
      float so = __builtin_amdgcn_rcpf(1.f + __builtin_amdgcn_exp2f(-oo * L2E));
      float tg = 1.f - 2.f * __builtin_amdgcn_rcpf(1.f + __builtin_amdgcn_exp2f(gg * CE));
      float cn = sf * c + si * tg;
      float tc = 1.f - 2.f * __builtin_amdgcn_rcpf(1.f + __builtin_amdgcn_exp2f(cn * CE));
      c_lds[tid] = cn;
      h_lds[tid] = so * tc;
    }
    __syncthreads();
    // ---- mel / stop partial heads (atomicAdd into zeroed f32 out) ----
    if (tid >= 128) {
      int cc = tid - 128;
      float xv = (cc < 64) ? h_lds[cc] : ctx_lds[s * 64 + (cc - 64)];
      stop_lds[cc] = StopT[s * 128 + cc] * xv;
    }
    if (tid < 80) {
      float a = (s == 0) ? mel_b[tid] : 0.f;
      const float* mp = MelT + (size_t)s * 10240 + tid;
#pragma unroll 8
      for (int cc = 0; cc < 128; ++cc) {
        float xv = (cc < 64) ? h_lds[cc] : ctx_lds[s * 64 + (cc - 64)];
        a = fmaf(mp[cc * 80], xv, a);
      }
      atomicAdd(&out[(size_t)b * 80000 + it * 80 + tid], a);
    }
    __syncthreads();
    if (tid == 0) {
      float st = (s == 0) ? stop_b[0] : 0.f;
      for (int i = 0; i < 128; ++i) st += stop_lds[i];
      atomicAdd(&out[(size_t)5120000 + b * 1000 + it], st);
    }
    // ---- next-step col-sliced partials from own h slice ----
    {
      int pn = par ^ 1;
      const float* wd = WdecT + (size_t)s * 16384 + tid;
      float acd = 0.f;
#pragma unroll 8
      for (int hh = 0; hh < 64; ++hh) acd = fmaf(wd[hh * 256], h_lds[hh], acd);
      agstore(decP + ((size_t)(pn * 64 + b) * 4 + s) * 256 + tid, acd);

      const float* wh = Whh4 + (size_t)s * 65536 + tid * 4;
      float g0 = 0, g1 = 0, g2 = 0, g3 = 0;
#pragma unroll 8
      for (int hh = 0; hh < 64; ++hh) {
        float4 wvv = *(const float4*)(wh + (size_t)hh * 1024);
        float hv = h_lds[hh];
        g0 = fmaf(wvv.x, hv, g0);
        g1 = fmaf(wvv.y, hv, g1);
        g2 = fmaf(wvv.z, hv, g2);
        g3 = fmaf(wvv.w, hv, g3);
      }
      float* gq = ghP + ((size_t)(pn * 64 + b) * 4 + s) * 1024 + tid * 4;
      agstore(gq + 0, g0);
      agstore(gq + 1, g1);
      agstore(gq + 2, g2);
      agstore(gq + 3, g3);
    }
    // ================= barrier 2 =================
    __threadfence();
    __syncthreads();
    if (tid == 0) {
      ++epoch;
      __hip_atomic_fetch_add(ctrb, 1u, __ATOMIC_RELEASE, __HIP_MEMORY_SCOPE_AGENT);
      while (__hip_atomic_load(ctrb, __ATOMIC_ACQUIRE, __HIP_MEMORY_SCOPE_AGENT) < 4u * epoch)
        __builtin_amdgcn_s_sleep(1);
    }
    __syncthreads();
    __threadfence();
  }
}

extern "C" void kernel_launch(void* const* d_in, const int* in_sizes, int n_in,
                              void* d_out, int out_size, void* d_ws, size_t ws_size,
                              hipStream_t stream) {
  const float* enc = (const float*)d_in[0];
  const float* tmel = (const float*)d_in[1];
  const float* W_enc = (const float*)d_in[2];
  const float* b_enc = (const float*)d_in[3];
  const float* W_dec = (const float*)d_in[4];
  const float* b_dec = (const float*)d_in[5];
  const float* v_w = (const float*)d_in[6];
  const float* v_b = (const float*)d_in[7];
  const float* pW1 = (const float*)d_in[8];
  const float* pb1 = (const float*)d_in[9];
  const float* pW2 = (const float*)d_in[10];
  const float* pb2 = (const float*)d_in[11];
  const float* W_ih = (const float*)d_in[12];
  const float* W_hh = (const float*)d_in[13];
  const float* b_ih = (const float*)d_in[14];
  const float* b_hh = (const float*)d_in[15];
  const float* mel_W = (const float*)d_in[16];
  const float* mel_b = (const float*)d_in[17];
  const float* stop_W = (const float*)d_in[18];
  const float* stop_b = (const float*)d_in[19];
  const float* emask = (const float*)d_in[20];

  if (ws_size < WS_NEED) return;  // fail-visible (stub-identical absmax) rather than corrupt

  char* ws = (char*)d_ws;
  float* attnT = (float*)(ws + OFF_ATTNT);
  unsigned short* pre2 = (unsigned short*)(ws + OFF_PRE2);
  float* Wic4 = (float*)(ws + OFF_WIC4);
  float* Wpre4 = (float*)(ws + OFF_WPRE4);
  float* Whh4 = (float*)(ws + OFF_WHH4);
  float* WdecT = (float*)(ws + OFF_WDECT);
  float* MelT = (float*)(ws + OFF_MELT);
  float* StopT = (float*)(ws + OFF_STOPT);
  float* biasG = (float*)(ws + OFF_BIASG);
  float* exch = (float*)(ws + OFF_EXCH);
  unsigned* ctr = (unsigned*)(exch + EXF_CTR);

  hipMemsetAsync(exch, 0, SZ_EXCH, stream);
  hipMemsetAsync(d_out, 0, (size_t)out_size * 4, stream);

  prep_weights<<<1446, 256, 0, stream>>>(W_ih, W_hh, W_dec, mel_W, stop_W, b_ih, b_hh,
                                         Wic4, Wpre4, Whh4, WdecT, MelT, StopT, biasG);
  attn_gemm<<<1024, 256, 0, stream>>>(enc, W_enc, b_enc, attnT);
  prenet_fused<<<1000, 256, 0, stream>>>(tmel, pW1, pb1, pW2, pb2, pre2);
  decoder_loop<<<256, 256, 0, stream>>>(attnT, enc, pre2, Wic4, Wpre4, Whh4, WdecT, MelT,
                                        StopT, biasG, exch, ctr, b_dec, v_w, v_b, emask,
                                        mel_b, stop_b, (float*)d_out);
}